// Round 4
// baseline (309.794 us; speedup 1.0000x reference)
//
#include <hip/hip_runtime.h>

// Locally-connected 2x2 conv, unshared weights.
// x: [256 planes, 512, 512] f32; weights: [511*511, 4]; bias: [511*511]
// out: [256, 511, 511]; out row 0 / col 0 are zero.
// neuron index = 511*w + h == flat in-plane output index.
//
// v4: thread = 4 cols x 2 rows (8 outputs). x loads are aligned float4 +
// 1 scalar per row (h0-1 % 4 == 0 by construction); middle x row reused in
// registers. Plane is the fastest grid dim (256 consecutive blocks share the
// same weight tile -> L2 hits). Nontemporal stores: out is never re-read,
// keep it out of L2/L3 so caches hold x/weights.

constexpr int W = 512;
constexpr int H = 512;
constexpr int OW = 511;
constexpr int OH = 511;
constexpr int PLANE_OUT = OW * OH;      // 261121
constexpr int PLANE_IN  = W * H;        // 262144

__global__ __launch_bounds__(256)
void lc_conv2x2_v4(const float* __restrict__ x,
                   const float4* __restrict__ weights,
                   const float* __restrict__ bias,
                   float* __restrict__ out) {
    const int p      = blockIdx.x;              // plane (fastest -> weight L2 reuse)
    const int lane_h = threadIdx.x & 127;       // 128 threads across h (4 cols each)
    const int lane_w = threadIdx.x >> 7;        // 2 row-pairs per block
    const int h0 = 1 + (lane_h << 2);           // 1,5,...,509 (h0-1 16B-aligned)
    const int w0 = 1 + (blockIdx.y << 2) + (lane_w << 1);   // rows 1..511
    const int w1 = w0 + 1;

    float*       op = out + (size_t)p * PLANE_OUT;
    const float* xp = x   + (size_t)p * PLANE_IN;

    // ---- border zeros (row 0 and col 0), every launch
    if (blockIdx.y == 0 && lane_w == 0) {
        #pragma unroll
        for (int j = 0; j < 4; ++j)
            if (h0 + j <= 510) __builtin_nontemporal_store(0.0f, op + h0 + j);
        if (lane_h == 0) __builtin_nontemporal_store(0.0f, op);
    }
    if (lane_h == 0) {
        if (w0 <= 510) __builtin_nontemporal_store(0.0f, op + (size_t)w0 * OH);
        if (w1 <= 510) __builtin_nontemporal_store(0.0f, op + (size_t)w1 * OH);
    }

    if (w0 > 510) return;                       // fully-masked row pair (tail)
    const bool v1 = (w1 <= 510);

    // ---- x: 3 rows feed 2 output rows; middle row register-reused
    const int hm  = h0 - 1;                     // aligned col start
    const int hs  = min(hm + 4, 511);           // clamped +4 scalar
    const int xr0 = w0 - 1;
    const int xr1 = w0;
    const int xr2 = min(w1, 511);

    float4 A  = *(const float4*)(xp + xr0 * H + hm);
    float  a4 = xp[xr0 * H + hs];
    float4 Bv = *(const float4*)(xp + xr1 * H + hm);
    float  b4 = xp[xr1 * H + hs];
    float4 Cv = *(const float4*)(xp + xr2 * H + hm);
    float  c4 = xp[xr2 * H + hs];

    float ra[5] = {A.x,  A.y,  A.z,  A.w,  a4};
    float rb[5] = {Bv.x, Bv.y, Bv.z, Bv.w, b4};
    float rc[5] = {Cv.x, Cv.y, Cv.z, Cv.w, c4};

    #pragma unroll
    for (int j = 0; j < 4; ++j) {
        const int  hh = min(h0 + j, 510);       // clamped for masked cols
        const bool hv = (h0 + j <= 510);

        const size_t g0  = (size_t)w0 * OH + hh;
        const float4 wt0 = weights[g0];
        const float  bv0 = bias[g0];
        const float  o0  = ra[j] * wt0.x + ra[j+1] * wt0.y
                         + rb[j] * wt0.z + rb[j+1] * wt0.w + bv0;
        if (hv) __builtin_nontemporal_store(o0, op + g0);

        if (v1) {
            const size_t g1  = (size_t)w1 * OH + hh;
            const float4 wt1 = weights[g1];
            const float  bv1 = bias[g1];
            const float  o1  = rb[j] * wt1.x + rb[j+1] * wt1.y
                             + rc[j] * wt1.z + rc[j+1] * wt1.w + bv1;
            if (hv) __builtin_nontemporal_store(o1, op + g1);
        }
    }
}

extern "C" void kernel_launch(void* const* d_in, const int* in_sizes, int n_in,
                              void* d_out, int out_size, void* d_ws, size_t ws_size,
                              hipStream_t stream) {
    const float*  x       = (const float*)d_in[0];
    const float4* weights = (const float4*)d_in[1];
    const float*  bias    = (const float*)d_in[2];
    float*        out     = (float*)d_out;

    int planes = in_sizes[0] / PLANE_IN;        // 256
    dim3 grid(planes, 128);                     // plane fastest; 128 x 4-row groups
    lc_conv2x2_v4<<<grid, 256, 0, stream>>>(x, weights, bias, out);
}

// Round 5
// 268.973 us; speedup vs baseline: 1.1518x; 1.1518x over previous
//
#include <hip/hip_runtime.h>

// Locally-connected 2x2 conv, unshared weights.
// x: [256 planes, 512, 512] f32; weights: [511*511, 4]; bias: [511*511]
// out: [256, 511, 511]; out row 0 / col 0 are zero.
// neuron index = 511*w + h == flat in-plane output index.
//
// v5 = v4 with PLAIN cached stores (v4's nontemporal scalar stores bypassed
// L2 write-combining -> 681MB HBM writes vs 261MB ideal). Loads unchanged:
// thread = 4 cols x 2 rows, aligned float4 + scalar x loads, middle row
// register-reused, plane-fastest grid for weight L2 sharing.

constexpr int W = 512;
constexpr int H = 512;
constexpr int OW = 511;
constexpr int OH = 511;
constexpr int PLANE_OUT = OW * OH;      // 261121
constexpr int PLANE_IN  = W * H;        // 262144

__global__ __launch_bounds__(256)
void lc_conv2x2_v5(const float* __restrict__ x,
                   const float4* __restrict__ weights,
                   const float* __restrict__ bias,
                   float* __restrict__ out) {
    const int p      = blockIdx.x;              // plane (fastest -> weight L2 reuse)
    const int lane_h = threadIdx.x & 127;       // 128 threads across h (4 cols each)
    const int lane_w = threadIdx.x >> 7;        // 2 row-pairs per block
    const int h0 = 1 + (lane_h << 2);           // 1,5,...,509 (h0-1 16B-aligned)
    const int w0 = 1 + (blockIdx.y << 2) + (lane_w << 1);   // rows 1..511
    const int w1 = w0 + 1;

    float*       op = out + (size_t)p * PLANE_OUT;
    const float* xp = x   + (size_t)p * PLANE_IN;

    // ---- border zeros (row 0 and col 0), every launch
    if (blockIdx.y == 0 && lane_w == 0) {
        #pragma unroll
        for (int j = 0; j < 4; ++j)
            if (h0 + j <= 510) op[h0 + j] = 0.0f;
        if (lane_h == 0) op[0] = 0.0f;
    }
    if (lane_h == 0) {
        if (w0 <= 510) op[(size_t)w0 * OH] = 0.0f;
        if (w1 <= 510) op[(size_t)w1 * OH] = 0.0f;
    }

    if (w0 > 510) return;                       // fully-masked row pair (tail)
    const bool v1 = (w1 <= 510);

    // ---- x: 3 rows feed 2 output rows; middle row register-reused
    const int hm  = h0 - 1;                     // aligned col start
    const int hs  = min(hm + 4, 511);           // clamped +4 scalar
    const int xr0 = w0 - 1;
    const int xr1 = w0;
    const int xr2 = min(w1, 511);

    float4 A  = *(const float4*)(xp + xr0 * H + hm);
    float  a4 = xp[xr0 * H + hs];
    float4 Bv = *(const float4*)(xp + xr1 * H + hm);
    float  b4 = xp[xr1 * H + hs];
    float4 Cv = *(const float4*)(xp + xr2 * H + hm);
    float  c4 = xp[xr2 * H + hs];

    float ra[5] = {A.x,  A.y,  A.z,  A.w,  a4};
    float rb[5] = {Bv.x, Bv.y, Bv.z, Bv.w, b4};
    float rc[5] = {Cv.x, Cv.y, Cv.z, Cv.w, c4};

    #pragma unroll
    for (int j = 0; j < 4; ++j) {
        const int  hh = min(h0 + j, 510);       // clamped for masked cols
        const bool hv = (h0 + j <= 510);

        const size_t g0  = (size_t)w0 * OH + hh;
        const float4 wt0 = weights[g0];
        const float  bv0 = bias[g0];
        const float  o0  = ra[j] * wt0.x + ra[j+1] * wt0.y
                         + rb[j] * wt0.z + rb[j+1] * wt0.w + bv0;
        if (hv) op[g0] = o0;

        if (v1) {
            const size_t g1  = (size_t)w1 * OH + hh;
            const float4 wt1 = weights[g1];
            const float  bv1 = bias[g1];
            const float  o1  = rb[j] * wt1.x + rb[j+1] * wt1.y
                             + rc[j] * wt1.z + rc[j+1] * wt1.w + bv1;
            if (hv) op[g1] = o1;
        }
    }
}

extern "C" void kernel_launch(void* const* d_in, const int* in_sizes, int n_in,
                              void* d_out, int out_size, void* d_ws, size_t ws_size,
                              hipStream_t stream) {
    const float*  x       = (const float*)d_in[0];
    const float4* weights = (const float4*)d_in[1];
    const float*  bias    = (const float*)d_in[2];
    float*        out     = (float*)d_out;

    int planes = in_sizes[0] / PLANE_IN;        // 256
    dim3 grid(planes, 128);                     // plane fastest; 128 x 4-row groups
    lc_conv2x2_v5<<<grid, 256, 0, stream>>>(x, weights, bias, out);
}

// Round 6
// 194.493 us; speedup vs baseline: 1.5928x; 1.3829x over previous
//
#include <hip/hip_runtime.h>

// Locally-connected 2x2 conv, unshared weights.
// x: [256 planes, 512, 512] f32; weights: [511*511, 4]; bias: [511*511]
// out: [256, 511, 511]; out row 0 / col 0 are zero.
// neuron index = 511*w + h == flat in-plane output index.
//
// v6: everything staged through LDS with global_load_lds (dense 16B/lane,
// fire-and-forget DMA). Block = 2 output rows x full width. For a row pair
// (w0, w0+1), weights/bias/out form ONE contiguous 1022-element span
// (flat = 511*w + h), so all staging is pure linear copy and all LDS reads /
// global stores are lane-contiguous (conflict-free, fully dense).

constexpr int W = 512;
constexpr int OW = 511;
constexpr int OH = 511;
constexpr int PLANE_OUT = OW * OH;      // 261121
constexpr int PLANE_IN  = W * W;        // 262144

#define AS1 __attribute__((address_space(1)))
#define AS3 __attribute__((address_space(3)))

__global__ __launch_bounds__(256)
void lc_conv2x2_v6(const float* __restrict__ x,
                   const float4* __restrict__ weights,
                   const float* __restrict__ bias,
                   float* __restrict__ out) {
    __shared__ float4 wt_lds[1024];     // weights[w0*511 .. +1024) (tail clamped)
    __shared__ float  bias_lds[1024];   // bias  [w0*511 .. +1024) (tail clamped)
    __shared__ float  x_lds[1536];      // x rows w0-1, w0, w0+1 (512 each)

    const int p   = blockIdx.x;         // plane (fastest -> weight L2 sharing)
    const int ty  = blockIdx.y;         // 0..254 row pairs
    const int w0  = 2 * ty + 1;         // 1,3,...,509 ; w1 = w0+1 <= 510 always

    const int tid  = threadIdx.x;
    const int wid  = tid >> 6;
    const int lane = tid & 63;

    const float* xp     = x + (size_t)p * PLANE_IN;
    const size_t wtbase = (size_t)w0 * OH;          // flat neuron base of row w0

    // ---- stage: 16 wt slices + 3+1 bias slices + 6 x slices, round-robin by wave
    for (int s = wid; s < 26; s += 4) {
        if (s < 16) {                               // weights: 1024 float4
            int f = (s << 6) + lane;
            size_t g = wtbase + (size_t)f;
            if (g > (size_t)(PLANE_OUT - 1)) g = (size_t)(PLANE_OUT - 1);
            __builtin_amdgcn_global_load_lds(
                (const AS1 void*)(weights + g),
                (AS3 void*)&wt_lds[s << 6], 16, 0, 0);
        } else if (s < 19) {                        // bias floats 0..767 (16B/lane)
            int b = s - 16;
            int f = (b << 6) + lane;                // float4 units
            size_t ge = wtbase + ((size_t)f << 2);
            __builtin_amdgcn_global_load_lds(
                (const AS1 void*)(bias + ge),
                (AS3 void*)&bias_lds[b << 8], 16, 0, 0);
        } else if (s == 19) {                       // bias floats 768..1023, 4B/lane
            #pragma unroll                          // (element-granular tail clamp)
            for (int q = 0; q < 4; ++q) {
                int fe = 768 + (q << 6) + lane;
                size_t ge = wtbase + (size_t)fe;
                if (ge > (size_t)(PLANE_OUT - 1)) ge = (size_t)(PLANE_OUT - 1);
                __builtin_amdgcn_global_load_lds(
                    (const AS1 void*)(bias + ge),
                    (AS3 void*)&bias_lds[768 + (q << 6)], 4, 0, 0);
            }
        } else {                                    // x rows w0-1..w0+1: 384 float4
            int xs = s - 20;
            int f = (xs << 6) + lane;
            const float* src = xp + (size_t)(w0 - 1) * W + ((size_t)f << 2);
            __builtin_amdgcn_global_load_lds(
                (const AS1 void*)src,
                (AS3 void*)&x_lds[xs << 8], 16, 0, 0);
        }
    }
    __syncthreads();                                // drains vmcnt before barrier

    float* op = out + (size_t)p * PLANE_OUT + wtbase;

    if (ty == 0) {                                  // row-0 border zeros
        for (int e = tid; e < OH; e += 256)
            out[(size_t)p * PLANE_OUT + e] = 0.0f;
    }

    // ---- compute: e = flat offset within the contiguous 1022-output span
    #pragma unroll
    for (int c = 0; c < 4; ++c) {
        int e = tid + (c << 8);
        if (e < 2 * OH) {
            int r = (e >= OH) ? 1 : 0;              // local row (w0 or w0+1)
            int h = e - (r ? OH : 0);               // output col
            float4 wt = wt_lds[e];                  // ds_read_b128, contiguous
            float  bv = bias_lds[e];
            int xb = (r << 9) + h;                  // 512*r + h
            int hm = (h == 0) ? xb : xb - 1;        // safe idx; unused when h==0
            float t0 = x_lds[hm];                   // x[w-1][h-1]
            float t1 = x_lds[xb];                   // x[w-1][h]
            float b0 = x_lds[hm + W];               // x[w][h-1]
            float b1 = x_lds[xb + W];               // x[w][h]
            float v = t0 * wt.x + t1 * wt.y + b0 * wt.z + b1 * wt.w + bv;
            op[e] = (h == 0) ? 0.0f : v;            // col-0 border zero
        }
    }
}

extern "C" void kernel_launch(void* const* d_in, const int* in_sizes, int n_in,
                              void* d_out, int out_size, void* d_ws, size_t ws_size,
                              hipStream_t stream) {
    const float*  x       = (const float*)d_in[0];
    const float4* weights = (const float4*)d_in[1];
    const float*  bias    = (const float*)d_in[2];
    float*        out     = (float*)d_out;

    int planes = in_sizes[0] / PLANE_IN;            // 256
    dim3 grid(planes, 255);                         // plane fastest; 255 row pairs
    lc_conv2x2_v6<<<grid, 256, 0, stream>>>(x, weights, bias, out);
}

// Round 7
// 146.982 us; speedup vs baseline: 2.1077x; 1.3232x over previous
//
#include <hip/hip_runtime.h>

// Locally-connected 2x2 conv, unshared weights.
// x: [256 planes, 512, 512] f32; weights: [511*511, 4]; bias: [511*511]
// out: [256, 511, 511]; out row 0 / col 0 are zero.
// neuron index = 511*w + h == flat in-plane output index.
//
// v7: grid-stride over planes. 2040 blocks (all co-resident): block =
// (tile, phase q); tile = row-pair x col-half; weights/bias for the tile
// loaded into registers ONCE, then the block sweeps planes q, q+4, ...
// => concurrent aggregate = a dense 4-plane window advancing linearly
// through x/out (the R0 streaming pattern that hit 4.1 TB/s), with weight
// HBM traffic ~21 MB total instead of 677 MB (R0) / L2-thrash (v5).
// All loads/stores scalar lane-dense (v3 style).

constexpr int W  = 512;
constexpr int OW = 511;
constexpr int OH = 511;
constexpr int PLANE_OUT = OW * OH;      // 261121
constexpr int PLANE_IN  = W * W;        // 262144
constexpr int PSTRIDE   = 4;            // concurrent plane window

__global__ __launch_bounds__(256, 8)    // force VGPR<=64: all 2040 blocks resident
void lc_conv2x2_v7(const float* __restrict__ x,
                   const float4* __restrict__ weights,
                   const float* __restrict__ bias,
                   float* __restrict__ out, int planes) {
    const int T    = blockIdx.x;                    // 0..509 tile
    const int q    = blockIdx.y;                    // 0..3 plane phase
    const int pair = T >> 1;                        // row-pair 0..254
    const int h    = ((T & 1) << 8) | threadIdx.x;  // 0..511
    if (h > 510) return;                            // col 511 doesn't exist
    const int w0 = 2 * pair + 1;                    // 1..509
    const int w1 = w0 + 1;                          // 2..510

    // weight/bias tile -> registers, once per block (loop-invariant)
    const int g0 = w0 * OH + h;                     // flat neuron/out index
    const int g1 = g0 + OH;
    const float4 wt0 = weights[g0];
    const float4 wt1 = weights[g1];
    const float  bv0 = bias[g0];
    const float  bv1 = bias[g1];

    const int  hm = (h == 0) ? 0 : h - 1;           // safe idx; lane0 masked at store
    const int  xa = (w0 - 1) * W;
    const int  xb = w0 * W;
    const int  xc = w1 * W;
    const bool hz = (h == 0);
    const bool r0 = (pair == 0);

    #pragma unroll 2
    for (int p = q; p < planes; p += PSTRIDE) {
        const float* xp = x   + (size_t)p * PLANE_IN;
        float*       op = out + (size_t)p * PLANE_OUT;

        float a0 = xp[xa + hm], a1 = xp[xa + h];
        float b0 = xp[xb + hm], b1 = xp[xb + h];
        float c0 = xp[xc + hm], c1 = xp[xc + h];

        float v0 = a0 * wt0.x + a1 * wt0.y + b0 * wt0.z + b1 * wt0.w + bv0;
        float v1 = b0 * wt1.x + b1 * wt1.y + c0 * wt1.z + c1 * wt1.w + bv1;

        op[g0] = hz ? 0.0f : v0;                    // col-0 border -> 0
        op[g1] = hz ? 0.0f : v1;
        if (r0) op[h] = 0.0f;                       // row-0 border, every plane
    }
}

extern "C" void kernel_launch(void* const* d_in, const int* in_sizes, int n_in,
                              void* d_out, int out_size, void* d_ws, size_t ws_size,
                              hipStream_t stream) {
    const float*  x       = (const float*)d_in[0];
    const float4* weights = (const float4*)d_in[1];
    const float*  bias    = (const float*)d_in[2];
    float*        out     = (float*)d_out;

    int planes = in_sizes[0] / PLANE_IN;            // 256
    dim3 grid(510, PSTRIDE);                        // 2040 blocks, all resident
    lc_conv2x2_v7<<<grid, 256, 0, stream>>>(x, weights, bias, out, planes);
}

// Round 8
// 139.645 us; speedup vs baseline: 2.2184x; 1.0525x over previous
//
#include <hip/hip_runtime.h>

// Locally-connected 2x2 conv, unshared weights.
// x: [256 planes, 512, 512] f32; weights: [511*511, 4]; bias: [511*511]
// out: [256, 511, 511]; out row 0 / col 0 are zero.
// neuron index = 511*w + h == flat in-plane output index.
//
// v8 = v7 (grid-stride planes, weights-in-registers, all blocks co-resident)
// with 2x2 outputs per thread and parity-aligned vector memory ops:
//   h0 odd  -> x float2 at col h0-1 is 8B-aligned (x row stride 512)
//   w0 odd  -> flat 511*w0+h0 is even -> row-w0 store is aligned float2
// Halves VMEM instructions per output and removes duplicate-byte lane
// requests (v7's hm/h overlap), raising bytes-in-flight per wave.

constexpr int W  = 512;
constexpr int OH = 511;
constexpr int PLANE_OUT = 511 * 511;    // 261121
constexpr int PLANE_IN  = 512 * 512;    // 262144
constexpr int PSTRIDE   = 8;            // concurrent plane window

__global__ __launch_bounds__(256, 8)    // <=64 VGPR: all 2040 blocks resident
void lc_conv2x2_v8(const float* __restrict__ x,
                   const float4* __restrict__ weights,
                   const float* __restrict__ bias,
                   float* __restrict__ out, int planes) {
    const int pair = blockIdx.x;                // 0..254 row-pair
    const int q    = blockIdx.y;                // 0..7 plane phase
    const int w0   = 2 * pair + 1;              // 1,3,...,509 (odd)
    const int w1   = w0 + 1;
    const int tid  = threadIdx.x;
    const bool act = (tid < 255);               // 255 threads x 2 cols = 510
    const int h0   = act ? (1 + 2 * tid) : 1;   // odd col start (clamped if idle)

    // ---- weights/bias -> registers, once per block
    const int g00 = w0 * OH + h0;               // even flat index
    const int g10 = g00 + OH;
    const float4 wt00 = weights[g00];
    const float4 wt01 = weights[g00 + 1];
    const float4 wt10 = weights[g10];
    const float4 wt11 = weights[g10 + 1];
    const float2 bA   = *(const float2*)(bias + g00);   // 8B-aligned (g00 even)
    const float  b10  = bias[g10];
    const float  b11  = bias[g10 + 1];

    const int xa = (w0 - 1) * W + h0 - 1;       // even col -> float2 aligned
    const int xb = xa + W;
    const int xc = xb + W;
    const bool r0 = (pair == 0);

    #pragma unroll 2
    for (int p = q; p < planes; p += PSTRIDE) {
        const float* xp = x   + (size_t)p * PLANE_IN;
        float*       op = out + (size_t)p * PLANE_OUT;

        if (act) {
            float2 A  = *(const float2*)(xp + xa);      // cols h0-1, h0
            float  A2 = xp[xa + 2];                     // col  h0+1
            float2 Bv = *(const float2*)(xp + xb);
            float  B2 = xp[xb + 2];
            float2 Cv = *(const float2*)(xp + xc);
            float  C2 = xp[xc + 2];

            float v00 = A.x * wt00.x + A.y * wt00.y + Bv.x * wt00.z + Bv.y * wt00.w + bA.x;
            float v01 = A.y * wt01.x + A2  * wt01.y + Bv.y * wt01.z + B2  * wt01.w + bA.y;
            float v10 = Bv.x * wt10.x + Bv.y * wt10.y + Cv.x * wt10.z + Cv.y * wt10.w + b10;
            float v11 = Bv.y * wt11.x + B2  * wt11.y + Cv.y * wt11.z + C2  * wt11.w + b11;

            *(float2*)(op + g00) = make_float2(v00, v01);   // aligned (g00 even)
            op[g10]     = v10;
            op[g10 + 1] = v11;
        } else {                                    // idle thread: col-0 borders
            op[(size_t)w0 * OH] = 0.0f;
            op[(size_t)w1 * OH] = 0.0f;
        }
        if (r0) {                                   // row-0 border, every plane
            int e = 2 * tid;
            if (e < OH - 1)      *(float2*)(op + e) = make_float2(0.0f, 0.0f);
            else if (e == OH - 1) op[e] = 0.0f;     // e == 510
        }
    }
}

extern "C" void kernel_launch(void* const* d_in, const int* in_sizes, int n_in,
                              void* d_out, int out_size, void* d_ws, size_t ws_size,
                              hipStream_t stream) {
    const float*  x       = (const float*)d_in[0];
    const float4* weights = (const float4*)d_in[1];
    const float*  bias    = (const float*)d_in[2];
    float*        out     = (float*)d_out;

    int planes = in_sizes[0] / PLANE_IN;            // 256
    dim3 grid(255, PSTRIDE);                        // 2040 blocks, all resident
    lc_conv2x2_v8<<<grid, 256, 0, stream>>>(x, weights, bias, out, planes);
}

// Round 9
// 139.576 us; speedup vs baseline: 2.2195x; 1.0005x over previous
//
#include <hip/hip_runtime.h>

// Locally-connected 2x2 conv, unshared weights.
// x: [256 planes, 512, 512] f32; weights: [511*511, 4]; bias: [511*511]
// out: [256, 511, 511]; out row 0 / col 0 are zero.
// neuron index = 511*w + h == flat in-plane output index.
//
// v9 = v8 with XCD-aware grid ordering. grid(8, 255): linear block id =
// q + 8*pair -> XCD = q under the %8 round-robin. Each XCD then runs all
// 255 row-pairs of ONE plane-phase: working set ~1-2MB (fits 4MB L2/XCD),
// halo-sharing pairs p,p+1 on the SAME XCD (halo = L2 hit), per-XCD
// read/write streams sweep linearly. 255 blocks/XCD = exact CU capacity.
// Kernel body byte-identical to v8.

constexpr int W  = 512;
constexpr int OH = 511;
constexpr int PLANE_OUT = 511 * 511;    // 261121
constexpr int PLANE_IN  = 512 * 512;    // 262144
constexpr int PSTRIDE   = 8;            // concurrent plane window = XCD count

__global__ __launch_bounds__(256, 8)    // <=64 VGPR: all 2040 blocks resident
void lc_conv2x2_v9(const float* __restrict__ x,
                   const float4* __restrict__ weights,
                   const float* __restrict__ bias,
                   float* __restrict__ out, int planes) {
    const int q    = blockIdx.x;                // 0..7 plane phase == XCD
    const int pair = blockIdx.y;                // 0..254 row-pair
    const int w0   = 2 * pair + 1;              // 1,3,...,509 (odd)
    const int w1   = w0 + 1;
    const int tid  = threadIdx.x;
    const bool act = (tid < 255);               // 255 threads x 2 cols = 510
    const int h0   = act ? (1 + 2 * tid) : 1;   // odd col start (clamped if idle)

    // ---- weights/bias -> registers, once per block
    const int g00 = w0 * OH + h0;               // even flat index
    const int g10 = g00 + OH;
    const float4 wt00 = weights[g00];
    const float4 wt01 = weights[g00 + 1];
    const float4 wt10 = weights[g10];
    const float4 wt11 = weights[g10 + 1];
    const float2 bA   = *(const float2*)(bias + g00);   // 8B-aligned (g00 even)
    const float  b10  = bias[g10];
    const float  b11  = bias[g10 + 1];

    const int xa = (w0 - 1) * W + h0 - 1;       // even col -> float2 aligned
    const int xb = xa + W;
    const int xc = xb + W;
    const bool r0 = (pair == 0);

    #pragma unroll 2
    for (int p = q; p < planes; p += PSTRIDE) {
        const float* xp = x   + (size_t)p * PLANE_IN;
        float*       op = out + (size_t)p * PLANE_OUT;

        if (act) {
            float2 A  = *(const float2*)(xp + xa);      // cols h0-1, h0
            float  A2 = xp[xa + 2];                     // col  h0+1
            float2 Bv = *(const float2*)(xp + xb);
            float  B2 = xp[xb + 2];
            float2 Cv = *(const float2*)(xp + xc);
            float  C2 = xp[xc + 2];

            float v00 = A.x * wt00.x + A.y * wt00.y + Bv.x * wt00.z + Bv.y * wt00.w + bA.x;
            float v01 = A.y * wt01.x + A2  * wt01.y + Bv.y * wt01.z + B2  * wt01.w + bA.y;
            float v10 = Bv.x * wt10.x + Bv.y * wt10.y + Cv.x * wt10.z + Cv.y * wt10.w + b10;
            float v11 = Bv.y * wt11.x + B2  * wt11.y + Cv.y * wt11.z + C2  * wt11.w + b11;

            *(float2*)(op + g00) = make_float2(v00, v01);   // aligned (g00 even)
            op[g10]     = v10;
            op[g10 + 1] = v11;
        } else {                                    // idle thread: col-0 borders
            op[(size_t)w0 * OH] = 0.0f;
            op[(size_t)w1 * OH] = 0.0f;
        }
        if (r0) {                                   // row-0 border, every plane
            int e = 2 * tid;
            if (e < OH - 1)      *(float2*)(op + e) = make_float2(0.0f, 0.0f);
            else if (e == OH - 1) op[e] = 0.0f;     // e == 510
        }
    }
}

extern "C" void kernel_launch(void* const* d_in, const int* in_sizes, int n_in,
                              void* d_out, int out_size, void* d_ws, size_t ws_size,
                              hipStream_t stream) {
    const float*  x       = (const float*)d_in[0];
    const float4* weights = (const float4*)d_in[1];
    const float*  bias    = (const float*)d_in[2];
    float*        out     = (float*)d_out;

    int planes = in_sizes[0] / PLANE_IN;            // 256
    dim3 grid(PSTRIDE, 255);                        // XCD = blockIdx.x under %8
    lc_conv2x2_v9<<<grid, 256, 0, stream>>>(x, weights, bias, out, planes);
}

// Round 10
// 136.839 us; speedup vs baseline: 2.2639x; 1.0200x over previous
//
#include <hip/hip_runtime.h>

// Locally-connected 2x2 conv, unshared weights.
// x: [256 planes, 512, 512] f32; weights: [511*511, 4]; bias: [511*511]
// out: [256, 511, 511]; out row 0 / col 0 are zero.
// neuron index = 511*w + h == flat in-plane output index.
//
// v10: flat-index decomposition -> every stream is dense dwordx4-class.
// Thread owns 4 consecutive flat outputs o0..o0+3 (o0 % 4 == 0):
//   store   = 1x float4 (dense, borders written as computed zeros)
//   weights = 4x float4 contiguous, in registers across the plane loop
//   x       = 2 rows x (dwordx4 + dwordx2) at base o0 + w - 513
// Row-boundary crossings (h+j >= 511) use plane-invariant per-j selects.
// Grid (8, 256): XCD = blockIdx.x under %8 (v9 mapping), 2048 blocks = exact
// residency; planes swept grid-stride (R7's linear-window pattern).

typedef float f4u __attribute__((ext_vector_type(4), aligned(4)));
typedef float f2u __attribute__((ext_vector_type(2), aligned(4)));

constexpr int PLANE_OUT = 511 * 511;    // 261121
constexpr int PLANE_IN  = 512 * 512;    // 262144
constexpr int PSTRIDE   = 8;            // plane phases == XCD count

__global__ __launch_bounds__(256, 8)    // <=64 VGPR: all 2048 blocks resident
void lc_conv2x2_v10(const float* __restrict__ x,
                    const float4* __restrict__ weights,
                    const float* __restrict__ bias,
                    float* __restrict__ out, int planes) {
    const int q = blockIdx.x;           // 0..7 plane phase == XCD
    const int b = blockIdx.y;           // 0..255
    const int t = threadIdx.x;

    if (b == 255) {                     // tail block: single output o = 261120
        if (t != 0) return;             // (w,h) = (510,510)
        const float4 wt = weights[PLANE_OUT - 1];
        const float  bv = bias[PLANE_OUT - 1];
        for (int p = q; p < planes; p += PSTRIDE) {
            const float* xp = x + (size_t)p * PLANE_IN;
            float v = xp[509 * 512 + 509] * wt.x + xp[509 * 512 + 510] * wt.y
                    + xp[510 * 512 + 509] * wt.z + xp[510 * 512 + 510] * wt.w + bv;
            out[(size_t)p * PLANE_OUT + (PLANE_OUT - 1)] = v;
        }
        return;
    }

    const int o0 = (b << 10) | (t << 2);        // 0..261116, multiple of 4
    const int w  = o0 / 511;                    // hoisted magic-div
    const int h  = o0 - w * 511;

    // plane-invariant per-j predicates: crossing + force-zero (borders)
    bool cj[4], zj[4];
    #pragma unroll
    for (int j = 0; j < 4; ++j) {
        const int hr = h + j;
        cj[j] = (hr >= 511);                    // crosses into row w+1
        const int wj = w + (cj[j] ? 1 : 0);
        const int hj = hr - (cj[j] ? 511 : 0);
        zj[j] = (wj == 0) || (hj == 0);         // row-0 / col-0 border
    }

    // weights/bias -> registers, once per block
    float4 wtr[4];
    #pragma unroll
    for (int j = 0; j < 4; ++j) wtr[j] = weights[o0 + j];
    const f4u bv4 = *(const f4u*)(bias + o0);

    // x bases: top-left of output o0 = flat(w-1, h-1) = o0 + w - 513
    int tb = o0 + w - 513;
    if (tb < 0) tb = 0;                         // w==0 rows are forced zero anyway
    const int bb = tb + 512;

    #pragma unroll 2
    for (int p = q; p < planes; p += PSTRIDE) {
        const float* xp = x + (size_t)p * PLANE_IN;

        f4u T0 = *(const f4u*)(xp + tb);        // top row: 6 floats
        f2u T1 = *(const f2u*)(xp + tb + 4);
        f4u B0 = *(const f4u*)(xp + bb);        // bottom row: 6 floats
        f2u B1 = *(const f2u*)(xp + bb + 4);
        const float tv[6] = {T0.x, T0.y, T0.z, T0.w, T1.x, T1.y};
        const float bv[6] = {B0.x, B0.y, B0.z, B0.w, B1.x, B1.y};

        f4u r;
        #pragma unroll
        for (int j = 0; j < 4; ++j) {           // static indices; cj -> cndmask
            const float xtl = cj[j] ? tv[j + 1] : tv[j];
            const float xtr = cj[j] ? tv[j + 2] : tv[j + 1];
            const float xbl = cj[j] ? bv[j + 1] : bv[j];
            const float xbr = cj[j] ? bv[j + 2] : bv[j + 1];
            const float v = xtl * wtr[j].x + xtr * wtr[j].y
                          + xbl * wtr[j].z + xbr * wtr[j].w + bv4[j];
            r[j] = zj[j] ? 0.0f : v;
        }
        *(f4u*)(out + (size_t)p * PLANE_OUT + o0) = r;  // dense dwordx4 stream
    }
}

extern "C" void kernel_launch(void* const* d_in, const int* in_sizes, int n_in,
                              void* d_out, int out_size, void* d_ws, size_t ws_size,
                              hipStream_t stream) {
    const float*  x       = (const float*)d_in[0];
    const float4* weights = (const float4*)d_in[1];
    const float*  bias    = (const float*)d_in[2];
    float*        out     = (float*)d_out;

    int planes = in_sizes[0] / PLANE_IN;        // 256
    dim3 grid(PSTRIDE, 256);                    // XCD = blockIdx.x under %8
    lc_conv2x2_v10<<<grid, 256, 0, stream>>>(x, weights, bias, out, planes);
}